// Round 4
// baseline (162.417 us; speedup 1.0000x reference)
//
#include <hip/hip_runtime.h>
#include <math.h>

// 14-qubit, 6-layer RX+CNOT-ring circuit, batch 512 — fully collapsed form.
//
// Verified chain (R3 passed end-to-end): with F_k = e^{i(W_k - Theta_k)},
//   out[b][q] = 2^-14 * sum_k cos( DW_k(b) - DTheta_k ),   where
//   DW_k     = W_k - W_{k^r_q} = sum_{pos in r_q} (bit_pos(k)? +x : -x)
//              -> depends on k ONLY via u = pext(k, r_q)   (p_q = popc bits)
//   DTheta_k = sum_{g : <r_q, m_g> odd} eps_g(k) * theta_g  (batch-independent)
// Binning k by u gives batch-independent tables
//   C^q_u = sum_{k in bin u} cos(DTheta_k),  S^q_u = sum sin(DTheta_k)
// and the per-batch output is the tiny bilinear form
//   out[b][q] = 2^-14 * sum_u [ cos(A_u) C^q_u + sin(A_u) S^q_u ],
//   A_u = sum_i (bit_i(u)? +x_{qb_i} : -x_{qb_i}).
// All masks/offsets computed constexpr from the same recurrence R3 verified.

#define NQ 14
#define DIM 16384
#define NLAYERS 6
#define NGATES (NLAYERS * NQ)   // 84, gate g = layer*NQ + q matches params order
#define BATCH 512
#define T2 256

constexpr int cpopc(unsigned v) { int c = 0; while (v) { c += (int)(v & 1u); v >>= 1; } return c; }

struct Tabs {
    unsigned short m[NGATES];        // gate masks (k-bit-position space)
    unsigned short r[NQ];            // readout lag masks
    int p[NQ];                       // popc(r[q])
    int off[NQ + 1];                 // bin-table offsets (prefix sums of 2^p)
    unsigned char qb[NQ][NQ];        // qubit index per set bit of r (LSB-first)
    int ng[NQ];                      // # gates with odd overlap vs r[q]
    unsigned short gmask[NQ][NGATES];
    unsigned char  gidx[NQ][NGATES];
};

constexpr Tabs gen_tabs() {
    Tabs T{};
    unsigned short C[NQ] = {}, R[NQ] = {};
    for (int q = 0; q < NQ; ++q) { C[q] = (unsigned short)(1u << (NQ - 1 - q)); R[q] = C[q]; }
    for (int l = 0; l < NLAYERS; ++l) {
        for (int q = 0; q < NQ; ++q) T.m[l * NQ + q] = C[q];
        for (int g = 0; g < NQ; ++g) {           // sequential — matches verified R2/R3
            int t = (g + 1) % NQ;
            C[g] ^= C[t];
            R[t] ^= R[g];
        }
    }
    for (int q = 0; q < NQ; ++q) T.r[q] = R[q];
    for (int q = 0; q < NQ; ++q) {
        int cnt = 0;
        for (int pos = 0; pos < NQ; ++pos)
            if ((R[q] >> pos) & 1u) { T.qb[q][cnt] = (unsigned char)(NQ - 1 - pos); ++cnt; }
        T.p[q] = cnt;
    }
    T.off[0] = 0;
    for (int q = 0; q < NQ; ++q) T.off[q + 1] = T.off[q] + (1 << T.p[q]);
    for (int q = 0; q < NQ; ++q) {
        int n = 0;
        for (int g = 0; g < NGATES; ++g) {
            if (cpopc((unsigned)(T.m[g] & R[q])) & 1) {
                T.gmask[q][n] = T.m[g];
                T.gidx[q][n]  = (unsigned char)g;
                ++n;
            }
        }
        T.ng[q] = n;
    }
    return T;
}
constexpr Tabs TAB = gen_tabs();

constexpr int calc_maxp() { int m = 0; for (int q = 0; q < NQ; ++q) if (TAB.p[q] > m) m = TAB.p[q]; return m; }
constexpr int MAXP  = calc_maxp();
constexpr int TOTAL = TAB.off[NQ];           // total bins across all q
static_assert(MAXP <= 13, "LDS bin arrays would overflow");
static_assert((size_t)TOTAL * 2u * 4u <= (1u << 21), "workspace guard: tables > 2 MB");

// -------- kernel 1: batch-independent bin tables C,S (one block per q) --------
__global__ __launch_bounds__(1024)
void build_tables(const float* __restrict__ params, float* __restrict__ tab)
{
    const int q   = blockIdx.x;
    const unsigned int r = TAB.r[q];
    const int nbins = 1 << TAB.p[q];
    const int off   = TAB.off[q];
    const int ng    = TAB.ng[q];

    __shared__ float th[NGATES];
    __shared__ float binC[1 << MAXP];
    __shared__ float binS[1 << MAXP];

    const int t = threadIdx.x;
    if (t < NGATES) th[t] = params[t];
    for (int i = t; i < nbins; i += 1024) { binC[i] = 0.0f; binS[i] = 0.0f; }
    __syncthreads();

    for (int kk = 0; kk < DIM / 1024; ++kk) {
        const int k = t + (kk << 10);
        double d = 0.0;                              // DTheta_k, fp64 accumulate
        for (int i = 0; i < ng; ++i) {
            const int mg   = (int)TAB.gmask[q][i];
            const float tg = th[TAB.gidx[q][i]];
            d += (__popc(k & mg) & 1) ? -(double)tg : (double)tg;
        }
        float s, c;
        sincosf((float)d, &s, &c);
        // u = pext(k, r)
        unsigned int u = 0, rr = r; int bi = 0;
        while (rr) {
            const int pos = __ffs(rr) - 1;
            u |= (((unsigned)k >> pos) & 1u) << bi;
            ++bi;
            rr &= rr - 1u;
        }
        atomicAdd(&binC[u], c);
        atomicAdd(&binS[u], s);
    }
    __syncthreads();
    for (int i = t; i < nbins; i += 1024) {
        tab[off + i]         = binC[i];
        tab[TOTAL + off + i] = binS[i];
    }
}

// -------- kernel 2: per-batch bilinear form (one block per batch element) ----
__global__ __launch_bounds__(T2)
void qout_kernel(const float* __restrict__ x, const float* __restrict__ tab,
                 float* __restrict__ out)
{
    __shared__ float sx[NQ];
    __shared__ float red[T2 / 64][NQ];

    const int b = blockIdx.x;
    const int t = threadIdx.x;
    if (t < NQ) sx[t] = x[b * NQ + t];
    __syncthreads();

    float acc[NQ];
    #pragma unroll
    for (int q = 0; q < NQ; ++q) acc[q] = 0.0f;

    #pragma unroll
    for (int q = 0; q < NQ; ++q) {               // after unroll, p/off/qb are literals
        const int nb  = 1 << TAB.p[q];
        const int off = TAB.off[q];
        for (int u = t; u < nb; u += T2) {
            float A = 0.0f;
            #pragma unroll
            for (int i = 0; i < TAB.p[q]; ++i) {
                const float xv = sx[TAB.qb[q][i]];
                A += ((u >> i) & 1) ? xv : -xv;
            }
            float s, c;
            sincosf(A, &s, &c);
            acc[q] += c * tab[off + u] + s * tab[TOTAL + off + u];
        }
    }

    #pragma unroll
    for (int q = 0; q < NQ; ++q) {
        #pragma unroll
        for (int o = 32; o > 0; o >>= 1)
            acc[q] += __shfl_down(acc[q], o, 64);
    }
    const int wave = t >> 6;
    const int lane = t & 63;
    if (lane == 0) {
        #pragma unroll
        for (int q = 0; q < NQ; ++q) red[wave][q] = acc[q];
    }
    __syncthreads();
    if (t < NQ) {
        float sum = 0.0f;
        #pragma unroll
        for (int w = 0; w < T2 / 64; ++w) sum += red[w][t];
        out[b * NQ + t] = sum * (1.0f / (float)DIM);
    }
}

extern "C" void kernel_launch(void* const* d_in, const int* in_sizes, int n_in,
                              void* d_out, int out_size, void* d_ws, size_t ws_size,
                              hipStream_t stream) {
    const float* x      = (const float*)d_in[0];   // (512, 14) float32
    const float* params = (const float*)d_in[1];   // (6, 1, 14) float32
    float* out          = (float*)d_out;           // (512, 14) float32
    float* tab          = (float*)d_ws;            // 2*TOTAL floats

    build_tables<<<NQ, 1024, 0, stream>>>(params, tab);
    qout_kernel<<<BATCH, T2, 0, stream>>>(x, tab, out);
}

// Round 7
// 144.065 us; speedup vs baseline: 1.1274x; 1.1274x over previous
//
#include <hip/hip_runtime.h>
#include <math.h>

// 14-qubit, 6-layer RX+CNOT-ring circuit, batch 512 — fully collapsed form.
//
// Verified chain (R3/R4 passed end-to-end):
//   out[b][q] = 2^-14 * sum_u [ cos(A_u) C^q_u + sin(A_u) S^q_u ]
//   A_u   = sum_i (bit_i(u) ? +x_{qb_i} : -x_{qb_i})      (per batch, tiny)
//   C^q_u = sum_{k: pext(k,r_q)=u} cos(DTheta_k)          (batch-independent)
//   S^q_u = likewise with sin
//   DTheta_k = sum_{g: <r_q,m_g> odd} (-1)^{popc(k&m_g)} theta_g
//
// R7: bit-exact R4 structure (14 blocks, one per q; LDS-atomic bins; plain
// global stores; NO pre-zero, NO global atomics — R5/R6's global-float-atomic
// merge into d_ws is the prime suspect for their failures and is removed).
// R4's measured problem (107 us, latency-bound on rodata loads in a serial
// fp64 chain, 2.2% occupancy) is fixed block-locally:
//   (a) gate list (mask,theta) staged once in LDS -> no global loads in loop
//   (b) loop interchange: gates outer, 16 k inner, 16 independent fp64
//       accumulators -> 16-way ILP instead of one dependent chain.

#define NQ 14
#define DIM 16384
#define NLAYERS 6
#define NGATES (NLAYERS * NQ)   // 84
#define BATCH 512
#define T2 256
#define KPT (DIM / 1024)        // 16 k-values per thread in build kernel

constexpr int cpopc(unsigned v) { int c = 0; while (v) { c += (int)(v & 1u); v >>= 1; } return c; }

struct Tabs {
    unsigned short m[NGATES];        // gate masks (k-bit-position space)
    unsigned short r[NQ];            // readout lag masks
    int p[NQ];                       // popc(r[q])
    int off[NQ + 1];                 // bin-table offsets (prefix sums of 2^p)
    unsigned char qb[NQ][NQ];        // qubit index per set bit of r (LSB-first)
    int ng[NQ];                      // # gates with odd overlap vs r[q]
    unsigned short gmask[NQ][NGATES];
    unsigned char  gidx[NQ][NGATES];
};

constexpr Tabs gen_tabs() {
    Tabs T{};
    unsigned short C[NQ] = {}, R[NQ] = {};
    for (int q = 0; q < NQ; ++q) { C[q] = (unsigned short)(1u << (NQ - 1 - q)); R[q] = C[q]; }
    for (int l = 0; l < NLAYERS; ++l) {
        for (int q = 0; q < NQ; ++q) T.m[l * NQ + q] = C[q];
        for (int g = 0; g < NQ; ++g) {           // sequential — matches verified R2/R3/R4
            int t = (g + 1) % NQ;
            C[g] ^= C[t];
            R[t] ^= R[g];
        }
    }
    for (int q = 0; q < NQ; ++q) T.r[q] = R[q];
    for (int q = 0; q < NQ; ++q) {
        int cnt = 0;
        for (int pos = 0; pos < NQ; ++pos)
            if ((R[q] >> pos) & 1u) { T.qb[q][cnt] = (unsigned char)(NQ - 1 - pos); ++cnt; }
        T.p[q] = cnt;
    }
    T.off[0] = 0;
    for (int q = 0; q < NQ; ++q) T.off[q + 1] = T.off[q] + (1 << T.p[q]);
    for (int q = 0; q < NQ; ++q) {
        int n = 0;
        for (int g = 0; g < NGATES; ++g) {
            if (cpopc((unsigned)(T.m[g] & R[q])) & 1) {
                T.gmask[q][n] = T.m[g];
                T.gidx[q][n]  = (unsigned char)g;
                ++n;
            }
        }
        T.ng[q] = n;
    }
    return T;
}
constexpr Tabs TAB = gen_tabs();

constexpr int calc_maxp() { int m = 0; for (int q = 0; q < NQ; ++q) if (TAB.p[q] > m) m = TAB.p[q]; return m; }
constexpr int MAXP  = calc_maxp();
constexpr int TOTAL = TAB.off[NQ];
static_assert(MAXP <= 8, "LDS bin arrays sized for p <= 8");

// -------- kernel 1: batch-independent bin tables C,S (one block per q) --------
__global__ __launch_bounds__(1024)
void build_tables(const float* __restrict__ params, float* __restrict__ tab)
{
    const int q     = blockIdx.x;
    const unsigned int r = TAB.r[q];
    const int nbins = 1 << TAB.p[q];
    const int off   = TAB.off[q];
    const int ng    = TAB.ng[q];

    __shared__ float sth[NGATES];                // theta per relevant gate
    __shared__ int   smask[NGATES];              // mask per relevant gate
    __shared__ float binC[1 << MAXP];
    __shared__ float binS[1 << MAXP];

    const int t = threadIdx.x;
    if (t < ng) {
        smask[t] = (int)TAB.gmask[q][t];
        sth[t]   = params[(int)TAB.gidx[q][t]];
    }
    for (int i = t; i < nbins; i += 1024) { binC[i] = 0.0f; binS[i] = 0.0f; }
    __syncthreads();

    // 16 k per thread, gates outer / k inner for 16-way ILP
    double d[KPT];
    #pragma unroll
    for (int kk = 0; kk < KPT; ++kk) d[kk] = 0.0;

    for (int i = 0; i < ng; ++i) {
        const int    mg = smask[i];              // LDS broadcast
        const double tg = (double)sth[i];
        #pragma unroll
        for (int kk = 0; kk < KPT; ++kk) {
            const int k = t + (kk << 10);
            d[kk] += (__popc(k & mg) & 1) ? -tg : tg;
        }
    }

    #pragma unroll
    for (int kk = 0; kk < KPT; ++kk) {
        const int k = t + (kk << 10);
        float s, c;
        sincosf((float)d[kk], &s, &c);
        // u = pext(k, r)  (R4-verified)
        unsigned int u = 0, rr = r; int bi = 0;
        while (rr) {
            const int pos = __ffs(rr) - 1;
            u |= (((unsigned)k >> pos) & 1u) << bi;
            ++bi;
            rr &= rr - 1u;
        }
        atomicAdd(&binC[u], c);                  // LDS atomics (R4-verified)
        atomicAdd(&binS[u], s);
    }
    __syncthreads();

    // plain global stores, exactly as the passing R4 (no pre-zero needed)
    for (int i = t; i < nbins; i += 1024) {
        tab[off + i]         = binC[i];
        tab[TOTAL + off + i] = binS[i];
    }
}

// -------- kernel 2: per-batch bilinear form (one block per batch element) ----
__global__ __launch_bounds__(T2)
void qout_kernel(const float* __restrict__ x, const float* __restrict__ tab,
                 float* __restrict__ out)
{
    __shared__ float sx[NQ];
    __shared__ float red[T2 / 64][NQ];

    const int b = blockIdx.x;
    const int t = threadIdx.x;
    if (t < NQ) sx[t] = x[b * NQ + t];
    __syncthreads();

    float acc[NQ];
    #pragma unroll
    for (int q = 0; q < NQ; ++q) acc[q] = 0.0f;

    #pragma unroll
    for (int q = 0; q < NQ; ++q) {               // after unroll, p/off/qb are literals
        const int nb  = 1 << TAB.p[q];
        const int off = TAB.off[q];
        for (int u = t; u < nb; u += T2) {
            float A = 0.0f;
            #pragma unroll
            for (int i = 0; i < TAB.p[q]; ++i) {
                const float xv = sx[TAB.qb[q][i]];
                A += ((u >> i) & 1) ? xv : -xv;
            }
            float s, c;
            sincosf(A, &s, &c);
            acc[q] += c * tab[off + u] + s * tab[TOTAL + off + u];
        }
    }

    #pragma unroll
    for (int q = 0; q < NQ; ++q) {
        #pragma unroll
        for (int o = 32; o > 0; o >>= 1)
            acc[q] += __shfl_down(acc[q], o, 64);
    }
    const int wave = t >> 6;
    const int lane = t & 63;
    if (lane == 0) {
        #pragma unroll
        for (int q = 0; q < NQ; ++q) red[wave][q] = acc[q];
    }
    __syncthreads();
    if (t < NQ) {
        float sum = 0.0f;
        #pragma unroll
        for (int w = 0; w < T2 / 64; ++w) sum += red[w][t];
        out[b * NQ + t] = sum * (1.0f / (float)DIM);
    }
}

extern "C" void kernel_launch(void* const* d_in, const int* in_sizes, int n_in,
                              void* d_out, int out_size, void* d_ws, size_t ws_size,
                              hipStream_t stream) {
    const float* x      = (const float*)d_in[0];   // (512, 14) float32
    const float* params = (const float*)d_in[1];   // (6, 1, 14) float32
    float* out          = (float*)d_out;           // (512, 14) float32
    float* tab          = (float*)d_ws;            // 2*TOTAL floats

    build_tables<<<NQ, 1024, 0, stream>>>(params, tab);
    qout_kernel<<<BATCH, T2, 0, stream>>>(x, tab, out);
}

// Round 9
// 137.391 us; speedup vs baseline: 1.1822x; 1.0486x over previous
//
#include <hip/hip_runtime.h>
#include <math.h>

// 14-qubit, 6-layer RX+CNOT-ring circuit, batch 512 — fully collapsed form.
//
// Verified chain (R3/R4/R7 passed end-to-end):
//   out[b][q] = 2^-14 * sum_u [ cos(A_u) C^q_u + sin(A_u) S^q_u ]
//   A_u   = sum_i (bit_i(u) ? +x_{qb_i} : -x_{qb_i})      (per batch, tiny)
//   C^q_u = sum_{k: pext(k,r_q)=u} cos(DTheta_k)          (batch-independent)
//   S^q_u = likewise with sin
//   DTheta_k = sum_{g: <r_q,m_g> odd} (-1)^{popc(k&m_g)} theta_g
//
// R9: SESSION RULE — tab is written by exactly ONE block per q (multi-block
// writers to d_ws failed deterministically in R5/R6/R8; mechanism unproven,
// pattern conclusive). Structure is byte-identical to the passing R7 except
// the per-thread d-computation: R7 did 2 LDS reads per (gate,kk) (672x2
// ds_read_b32/thread -> LDS-pipe bound, 86 us). Since k = t + (kk<<10):
//   parity(k & m) = parity(t & m&1023) XOR parity(kk & (m>>10))
// so each gate is read ONCE, a = +-theta resolved from the t-part, and the
// 16 kk-accumulators update with pure register ops (kk literal after unroll).

#define NQ 14
#define DIM 16384
#define NLAYERS 6
#define NGATES (NLAYERS * NQ)   // 84
#define BATCH 512
#define T2 256
#define KPT (DIM / 1024)        // 16 k-values per thread in build kernel

constexpr int cpopc(unsigned v) { int c = 0; while (v) { c += (int)(v & 1u); v >>= 1; } return c; }

struct Tabs {
    unsigned short m[NGATES];        // gate masks (k-bit-position space)
    unsigned short r[NQ];            // readout lag masks
    int p[NQ];                       // popc(r[q])
    int off[NQ + 1];                 // bin-table offsets (prefix sums of 2^p)
    unsigned char qb[NQ][NQ];        // qubit index per set bit of r (LSB-first)
    int ng[NQ];                      // # gates with odd overlap vs r[q]
    unsigned short gmask[NQ][NGATES];
    unsigned char  gidx[NQ][NGATES];
};

constexpr Tabs gen_tabs() {
    Tabs T{};
    unsigned short C[NQ] = {}, R[NQ] = {};
    for (int q = 0; q < NQ; ++q) { C[q] = (unsigned short)(1u << (NQ - 1 - q)); R[q] = C[q]; }
    for (int l = 0; l < NLAYERS; ++l) {
        for (int q = 0; q < NQ; ++q) T.m[l * NQ + q] = C[q];
        for (int g = 0; g < NQ; ++g) {           // sequential — matches verified R2/R3/R4/R7
            int t = (g + 1) % NQ;
            C[g] ^= C[t];
            R[t] ^= R[g];
        }
    }
    for (int q = 0; q < NQ; ++q) T.r[q] = R[q];
    for (int q = 0; q < NQ; ++q) {
        int cnt = 0;
        for (int pos = 0; pos < NQ; ++pos)
            if ((R[q] >> pos) & 1u) { T.qb[q][cnt] = (unsigned char)(NQ - 1 - pos); ++cnt; }
        T.p[q] = cnt;
    }
    T.off[0] = 0;
    for (int q = 0; q < NQ; ++q) T.off[q + 1] = T.off[q] + (1 << T.p[q]);
    for (int q = 0; q < NQ; ++q) {
        int n = 0;
        for (int g = 0; g < NGATES; ++g) {
            if (cpopc((unsigned)(T.m[g] & R[q])) & 1) {
                T.gmask[q][n] = T.m[g];
                T.gidx[q][n]  = (unsigned char)g;
                ++n;
            }
        }
        T.ng[q] = n;
    }
    return T;
}
constexpr Tabs TAB = gen_tabs();

constexpr int calc_maxp() { int m = 0; for (int q = 0; q < NQ; ++q) if (TAB.p[q] > m) m = TAB.p[q]; return m; }
constexpr int MAXP  = calc_maxp();
constexpr int TOTAL = TAB.off[NQ];
static_assert(MAXP <= 8, "LDS bin arrays sized for p <= 8");

// -------- kernel 1: batch-independent bin tables C,S (one block per q) --------
__global__ __launch_bounds__(1024)
void build_tables(const float* __restrict__ params, float* __restrict__ tab)
{
    const int q     = blockIdx.x;
    const unsigned int r = TAB.r[q];
    const int nbins = 1 << TAB.p[q];
    const int off   = TAB.off[q];
    const int ng    = TAB.ng[q];

    __shared__ float sth[NGATES];                // theta per relevant gate
    __shared__ int   smask[NGATES];              // mask per relevant gate
    __shared__ float binC[1 << MAXP];
    __shared__ float binS[1 << MAXP];

    const int t = threadIdx.x;
    if (t < ng) {
        smask[t] = (int)TAB.gmask[q][t];
        sth[t]   = params[(int)TAB.gidx[q][t]];
    }
    for (int i = t; i < nbins; i += 1024) { binC[i] = 0.0f; binS[i] = 0.0f; }
    __syncthreads();

    // k = t + (kk << 10);  parity(k&m) = parity(t & m&1023) ^ parity(kk & m>>10).
    // One LDS read pair per gate; 16 independent register accumulators.
    double d[KPT];
    #pragma unroll
    for (int kk = 0; kk < KPT; ++kk) d[kk] = 0.0;

    for (int i = 0; i < ng; ++i) {
        const int   mg = smask[i];               // LDS broadcast, once per gate
        const float tg = sth[i];
        const int   slow = __popc(t & (mg & 1023)) & 1;
        const double a  = slow ? -(double)tg : (double)tg;
        const double na = -a;
        const int   mh = mg >> 10;               // 4-bit kk-mask
        #pragma unroll
        for (int kk = 0; kk < KPT; ++kk) {
            d[kk] += (__popc(kk & mh) & 1) ? na : a;   // kk literal after unroll
        }
    }

    #pragma unroll
    for (int kk = 0; kk < KPT; ++kk) {
        const int k = t + (kk << 10);
        float s, c;
        sincosf((float)d[kk], &s, &c);
        // u = pext(k, r)  (R4/R7-verified)
        unsigned int u = 0, rr = r; int bi = 0;
        while (rr) {
            const int pos = __ffs(rr) - 1;
            u |= (((unsigned)k >> pos) & 1u) << bi;
            ++bi;
            rr &= rr - 1u;
        }
        atomicAdd(&binC[u], c);                  // LDS atomics (R4/R7-verified)
        atomicAdd(&binS[u], s);
    }
    __syncthreads();

    // plain global stores, exactly as the passing R4/R7 (single writer per q)
    for (int i = t; i < nbins; i += 1024) {
        tab[off + i]         = binC[i];
        tab[TOTAL + off + i] = binS[i];
    }
}

// -------- kernel 2: per-batch bilinear form (one block per batch element) ----
__global__ __launch_bounds__(T2)
void qout_kernel(const float* __restrict__ x, const float* __restrict__ tab,
                 float* __restrict__ out)
{
    __shared__ float sx[NQ];
    __shared__ float red[T2 / 64][NQ];

    const int b = blockIdx.x;
    const int t = threadIdx.x;
    if (t < NQ) sx[t] = x[b * NQ + t];
    __syncthreads();

    float acc[NQ];
    #pragma unroll
    for (int q = 0; q < NQ; ++q) acc[q] = 0.0f;

    #pragma unroll
    for (int q = 0; q < NQ; ++q) {               // after unroll, p/off/qb are literals
        const int nb  = 1 << TAB.p[q];
        const int off = TAB.off[q];
        for (int u = t; u < nb; u += T2) {
            float A = 0.0f;
            #pragma unroll
            for (int i = 0; i < TAB.p[q]; ++i) {
                const float xv = sx[TAB.qb[q][i]];
                A += ((u >> i) & 1) ? xv : -xv;
            }
            float s, c;
            sincosf(A, &s, &c);
            acc[q] += c * tab[off + u] + s * tab[TOTAL + off + u];
        }
    }

    #pragma unroll
    for (int q = 0; q < NQ; ++q) {
        #pragma unroll
        for (int o = 32; o > 0; o >>= 1)
            acc[q] += __shfl_down(acc[q], o, 64);
    }
    const int wave = t >> 6;
    const int lane = t & 63;
    if (lane == 0) {
        #pragma unroll
        for (int q = 0; q < NQ; ++q) red[wave][q] = acc[q];
    }
    __syncthreads();
    if (t < NQ) {
        float sum = 0.0f;
        #pragma unroll
        for (int w = 0; w < T2 / 64; ++w) sum += red[w][t];
        out[b * NQ + t] = sum * (1.0f / (float)DIM);
    }
}

extern "C" void kernel_launch(void* const* d_in, const int* in_sizes, int n_in,
                              void* d_out, int out_size, void* d_ws, size_t ws_size,
                              hipStream_t stream) {
    const float* x      = (const float*)d_in[0];   // (512, 14) float32
    const float* params = (const float*)d_in[1];   // (6, 1, 14) float32
    float* out          = (float*)d_out;           // (512, 14) float32
    float* tab          = (float*)d_ws;            // 2*TOTAL floats

    build_tables<<<NQ, 1024, 0, stream>>>(params, tab);
    qout_kernel<<<BATCH, T2, 0, stream>>>(x, tab, out);
}

// Round 10
// 90.898 us; speedup vs baseline: 1.7868x; 1.5115x over previous
//
#include <hip/hip_runtime.h>
#include <math.h>

// 14-qubit, 6-layer RX+CNOT-ring circuit, batch 512 — fully collapsed form.
//
// Verified chain (R3/R4/R7/R9 passed end-to-end):
//   out[b][q] = 2^-14 * sum_u [ cos(A_u) C^q_u + sin(A_u) S^q_u ]
//   C^q_u = sum_{k: pext(k,r_q)=u} cos(DTheta_k),  S^q_u likewise with sin
//   DTheta_k = sum_{g: <r_q,m_g> odd} (-1)^{popc(k&m_g)} theta_g
//
// R10: kill the fp64 chains + per-k sincos with unit-complex algebra.
// k = t + (kk<<10). Group gates by mh = m>>10 (16 classes):
//   P[h] = sum_{mh=h} (-1)^{popc(t & m&1023)} theta   ->  d[kk] = WHT_4(P)[kk]
// Exponentiate: e^{i d[kk]} = product-WHT of e^{i P[h]}, butterfly
// (A,B) -> (A*B, A*conj(B)). e^{i P[h]} = product of precomputed e^{+-i theta}
// (ng sincosf per BLOCK, not 16 per thread). Gate masks are compile-time ->
// body templated on q (14-way switch) with recursive gates<Q,I> so bucket
// index mh is a literal: 16 complex buckets stay in registers; the compiler
// cannot re-interchange this into a serial chain (R7/R9's failure mode).
// Epilogue: constexpr kk-groups pre-summed in registers, then LDS atomics
// into per-wave bin replicas; merge; plain stores. SESSION RULE intact:
// tab written by exactly ONE block per q (multi-block writers failed R5/R6/R8).

#define NQ 14
#define DIM 16384
#define NLAYERS 6
#define NGATES (NLAYERS * NQ)   // 84
#define BATCH 512
#define T2 256
#define TB 1024                 // build threads
#define NREP 16                 // bin replicas, one per wave

constexpr int cpopc(unsigned v) { int c = 0; while (v) { c += (int)(v & 1u); v >>= 1; } return c; }

__host__ __device__ constexpr unsigned cdep(unsigned v, unsigned m) {
    // deposit LSB-first: bit b of v -> b-th set position of m
    unsigned r = 0; int b = 0;
    for (int pos = 0; pos < 16; ++pos)
        if ((m >> pos) & 1u) { r |= ((v >> b) & 1u) << pos; ++b; }
    return r;
}

struct Tabs {
    unsigned short m[NGATES];        // gate masks (k-bit-position space)
    unsigned short r[NQ];            // readout lag masks
    int p[NQ];                       // popc(r[q])
    int off[NQ + 1];                 // bin-table offsets (prefix sums of 2^p)
    unsigned char qb[NQ][NQ];        // qubit index per set bit of r (LSB-first)
    int ng[NQ];                      // # gates with odd overlap vs r[q]
    unsigned short gmask[NQ][NGATES];
    unsigned char  gidx[NQ][NGATES];
};

constexpr Tabs gen_tabs() {
    Tabs T{};
    unsigned short C[NQ] = {}, R[NQ] = {};
    for (int q = 0; q < NQ; ++q) { C[q] = (unsigned short)(1u << (NQ - 1 - q)); R[q] = C[q]; }
    for (int l = 0; l < NLAYERS; ++l) {
        for (int q = 0; q < NQ; ++q) T.m[l * NQ + q] = C[q];
        for (int g = 0; g < NQ; ++g) {           // sequential — matches verified R2/R3/R4/R7/R9
            int t = (g + 1) % NQ;
            C[g] ^= C[t];
            R[t] ^= R[g];
        }
    }
    for (int q = 0; q < NQ; ++q) T.r[q] = R[q];
    for (int q = 0; q < NQ; ++q) {
        int cnt = 0;
        for (int pos = 0; pos < NQ; ++pos)
            if ((R[q] >> pos) & 1u) { T.qb[q][cnt] = (unsigned char)(NQ - 1 - pos); ++cnt; }
        T.p[q] = cnt;
    }
    T.off[0] = 0;
    for (int q = 0; q < NQ; ++q) T.off[q + 1] = T.off[q] + (1 << T.p[q]);
    for (int q = 0; q < NQ; ++q) {
        int n = 0;
        for (int g = 0; g < NGATES; ++g) {
            if (cpopc((unsigned)(T.m[g] & R[q])) & 1) {
                T.gmask[q][n] = T.m[g];
                T.gidx[q][n]  = (unsigned char)g;
                ++n;
            }
        }
        T.ng[q] = n;
    }
    return T;
}
constexpr Tabs TAB = gen_tabs();

constexpr int calc_maxp() { int m = 0; for (int q = 0; q < NQ; ++q) if (TAB.p[q] > m) m = TAB.p[q]; return m; }
constexpr int MAXP  = calc_maxp();
constexpr int TOTAL = TAB.off[NQ];
static_assert(MAXP <= 8, "bin replica arrays sized for p <= 8");

// ---- recursive gate product: literal bucket index mh, registers only ----
template<int Q, int I>
__device__ __forceinline__ void gates(const float2* __restrict__ w, int t,
                                      float (&Bx)[16], float (&By)[16])
{
    if constexpr (I < TAB.ng[Q]) {
        constexpr int mg = (int)TAB.gmask[Q][I];
        constexpr int ml = mg & 1023;
        constexpr int mh = mg >> 10;
        const float2 wv = w[I];                       // ds_read_b64 broadcast
        const float si = (__popc(t & ml) & 1) ? -wv.y : wv.y;
        const float c  = wv.x;
        const float nx = Bx[mh] * c - By[mh] * si;
        const float ny = Bx[mh] * si + By[mh] * c;
        Bx[mh] = nx; By[mh] = ny;
        gates<Q, I + 1>(w, t, Bx, By);
    }
}

template<int Q>
__device__ __forceinline__ void build_q(const float2* __restrict__ w,
                                        float* __restrict__ binC,
                                        float* __restrict__ binS, int t)
{
    constexpr unsigned r   = TAB.r[Q];
    constexpr unsigned rl  = r & 1023u;
    constexpr unsigned rh  = (r >> 10) & 15u;
    constexpr int      pl  = cpopc(rl);
    constexpr int      ph  = cpopc(rh);
    constexpr int      NU  = 1 << ph;            // distinct high-bin values
    constexpr int      MPG = 16 >> ph;           // kk's per bin group
    constexpr unsigned nrh = (~rh) & 15u;

    // phase 1: 16 complex buckets B[h] = e^{i P[h]}
    float Bx[16], By[16];
    #pragma unroll
    for (int h = 0; h < 16; ++h) { Bx[h] = 1.0f; By[h] = 0.0f; }
    gates<Q, 0>(w, t, Bx, By);

    // phase 2: product-WHT -> B[kk] = (cos d[kk], sin d[kk])
    #pragma unroll
    for (int s = 1; s < 16; s <<= 1) {
        #pragma unroll
        for (int h = 0; h < 16; ++h) {
            if (!(h & s)) {
                const int h1 = h | s;
                const float p1 = Bx[h] * Bx[h1], p2 = By[h] * By[h1];
                const float p3 = Bx[h] * By[h1], p4 = By[h] * Bx[h1];
                Bx[h]  = p1 - p2;  By[h]  = p3 + p4;   // A*B
                Bx[h1] = p1 + p2;  By[h1] = p4 - p3;   // A*conj(B)
            }
        }
    }

    // phase 3: ulow = pext(t, rl) (literal mask -> unrolled)
    unsigned ulow = 0;
    {
        int bi = 0;
        #pragma unroll
        for (int pos = 0; pos < 10; ++pos)
            if ((rl >> pos) & 1u) { ulow |= (((unsigned)t >> pos) & 1u) << bi; ++bi; }
    }
    const int rep = t >> 6;                      // per-wave replica
    float* bc = binC + (rep << MAXP);
    float* bs = binS + (rep << MAXP);

    #pragma unroll
    for (int uh = 0; uh < NU; ++uh) {            // constexpr kk-groups
        float fx = 0.0f, fy = 0.0f;
        #pragma unroll
        for (int mm = 0; mm < MPG; ++mm) {
            const int kk = (int)(cdep((unsigned)uh, rh) | cdep((unsigned)mm, nrh));
            fx += Bx[kk]; fy += By[kk];
        }
        const unsigned u = ulow | ((unsigned)uh << pl);
        atomicAdd(&bc[u], fx);
        atomicAdd(&bs[u], fy);
    }
}

// -------- kernel 1: batch-independent bin tables C,S (one block per q) --------
__global__ __launch_bounds__(TB, 4)
void build_tables(const float* __restrict__ params, float* __restrict__ tab)
{
    __shared__ float2 w[NGATES];                 // e^{i theta} per relevant gate
    __shared__ float  binC[NREP << MAXP];
    __shared__ float  binS[NREP << MAXP];

    const int q = blockIdx.x;
    const int t = threadIdx.x;
    const int ng = TAB.ng[q];

    if (t < ng) {
        const float th = params[(int)TAB.gidx[q][t]];
        float s, c; sincosf(th, &s, &c);
        w[t] = make_float2(c, s);
    }
    for (int i = t; i < (NREP << MAXP); i += TB) { binC[i] = 0.0f; binS[i] = 0.0f; }
    __syncthreads();

    switch (q) {
        case 0:  build_q<0 >(w, binC, binS, t); break;
        case 1:  build_q<1 >(w, binC, binS, t); break;
        case 2:  build_q<2 >(w, binC, binS, t); break;
        case 3:  build_q<3 >(w, binC, binS, t); break;
        case 4:  build_q<4 >(w, binC, binS, t); break;
        case 5:  build_q<5 >(w, binC, binS, t); break;
        case 6:  build_q<6 >(w, binC, binS, t); break;
        case 7:  build_q<7 >(w, binC, binS, t); break;
        case 8:  build_q<8 >(w, binC, binS, t); break;
        case 9:  build_q<9 >(w, binC, binS, t); break;
        case 10: build_q<10>(w, binC, binS, t); break;
        case 11: build_q<11>(w, binC, binS, t); break;
        case 12: build_q<12>(w, binC, binS, t); break;
        case 13: build_q<13>(w, binC, binS, t); break;
    }
    __syncthreads();

    // merge replicas; plain global stores (single writer per q — session rule)
    const int nbins = 1 << TAB.p[q];
    const int off   = TAB.off[q];
    for (int i = t; i < nbins; i += TB) {
        float sc = 0.0f, ss = 0.0f;
        #pragma unroll
        for (int rp = 0; rp < NREP; ++rp) {
            sc += binC[(rp << MAXP) + i];
            ss += binS[(rp << MAXP) + i];
        }
        tab[off + i]         = sc;
        tab[TOTAL + off + i] = ss;
    }
}

// -------- kernel 2: per-batch bilinear form (unchanged, R4/R7/R9-verified) ----
__global__ __launch_bounds__(T2)
void qout_kernel(const float* __restrict__ x, const float* __restrict__ tab,
                 float* __restrict__ out)
{
    __shared__ float sx[NQ];
    __shared__ float red[T2 / 64][NQ];

    const int b = blockIdx.x;
    const int t = threadIdx.x;
    if (t < NQ) sx[t] = x[b * NQ + t];
    __syncthreads();

    float acc[NQ];
    #pragma unroll
    for (int q = 0; q < NQ; ++q) acc[q] = 0.0f;

    #pragma unroll
    for (int q = 0; q < NQ; ++q) {               // after unroll, p/off/qb are literals
        const int nb  = 1 << TAB.p[q];
        const int off = TAB.off[q];
        for (int u = t; u < nb; u += T2) {
            float A = 0.0f;
            #pragma unroll
            for (int i = 0; i < TAB.p[q]; ++i) {
                const float xv = sx[TAB.qb[q][i]];
                A += ((u >> i) & 1) ? xv : -xv;
            }
            float s, c;
            sincosf(A, &s, &c);
            acc[q] += c * tab[off + u] + s * tab[TOTAL + off + u];
        }
    }

    #pragma unroll
    for (int q = 0; q < NQ; ++q) {
        #pragma unroll
        for (int o = 32; o > 0; o >>= 1)
            acc[q] += __shfl_down(acc[q], o, 64);
    }
    const int wave = t >> 6;
    const int lane = t & 63;
    if (lane == 0) {
        #pragma unroll
        for (int q = 0; q < NQ; ++q) red[wave][q] = acc[q];
    }
    __syncthreads();
    if (t < NQ) {
        float sum = 0.0f;
        #pragma unroll
        for (int w = 0; w < T2 / 64; ++w) sum += red[w][t];
        out[b * NQ + t] = sum * (1.0f / (float)DIM);
    }
}

extern "C" void kernel_launch(void* const* d_in, const int* in_sizes, int n_in,
                              void* d_out, int out_size, void* d_ws, size_t ws_size,
                              hipStream_t stream) {
    const float* x      = (const float*)d_in[0];   // (512, 14) float32
    const float* params = (const float*)d_in[1];   // (6, 1, 14) float32
    float* out          = (float*)d_out;           // (512, 14) float32
    float* tab          = (float*)d_ws;            // 2*TOTAL floats

    build_tables<<<NQ, TB, 0, stream>>>(params, tab);
    qout_kernel<<<BATCH, T2, 0, stream>>>(x, tab, out);
}

// Round 11
// 72.166 us; speedup vs baseline: 2.2506x; 1.2596x over previous
//
#include <hip/hip_runtime.h>
#include <math.h>

// 14-qubit, 6-layer RX+CNOT-ring circuit, batch 512 — fully collapsed form.
//
// Verified chain (R3/R4/R7/R9/R10 passed end-to-end):
//   out[b][q] = 2^-14 * sum_u [ cos(A_u) C^q_u + sin(A_u) S^q_u ]
//   C^q_u = sum_{k: pext(k,r_q)=u} cos(DTheta_k),  S^q_u likewise with sin
//   DTheta_k = sum_{g: <r_q,m_g> odd} (-1)^{popc(k&m_g)} theta_g
//
// R10 structure: unit-complex algebra. k = t + (kk<<10); gates grouped by
// mh = m>>10 into 16 register buckets B[h] = e^{i P[h]} (template-recursive,
// literal indices); product-WHT butterfly (A,B)->(A*B, A*conj(B)) yields
// e^{i d[kk]}; constexpr kk-groups pre-summed; per-wave LDS bin replicas.
//
// R11 (this round): phase-3 fix. R10's ~33 us was intra-wave SAME-ADDRESS
// LDS-atomic serialization: for q with few rl bits in the lane range,
// 32-64 lanes hit one bin address (up to 64-way RMW serialization x 16
// waves through one LDS pipe). Fix: group-mate lanes differ exactly in the
// constexpr bits dmask = 63 & ~rl -> butterfly-reduce (fx,fy) over dmask
// via __shfl_xor, then ONE lane per address per wave issues the atomic.
// SESSION RULE intact: tab written by exactly ONE block per q (multi-block
// writers to d_ws failed deterministically R5/R6/R8).

#define NQ 14
#define DIM 16384
#define NLAYERS 6
#define NGATES (NLAYERS * NQ)   // 84
#define BATCH 512
#define T2 256
#define TB 1024                 // build threads
#define NREP 16                 // bin replicas, one per wave

constexpr int cpopc(unsigned v) { int c = 0; while (v) { c += (int)(v & 1u); v >>= 1; } return c; }

__host__ __device__ constexpr unsigned cdep(unsigned v, unsigned m) {
    // deposit LSB-first: bit b of v -> b-th set position of m
    unsigned r = 0; int b = 0;
    for (int pos = 0; pos < 16; ++pos)
        if ((m >> pos) & 1u) { r |= ((v >> b) & 1u) << pos; ++b; }
    return r;
}

struct Tabs {
    unsigned short m[NGATES];        // gate masks (k-bit-position space)
    unsigned short r[NQ];            // readout lag masks
    int p[NQ];                       // popc(r[q])
    int off[NQ + 1];                 // bin-table offsets (prefix sums of 2^p)
    unsigned char qb[NQ][NQ];        // qubit index per set bit of r (LSB-first)
    int ng[NQ];                      // # gates with odd overlap vs r[q]
    unsigned short gmask[NQ][NGATES];
    unsigned char  gidx[NQ][NGATES];
};

constexpr Tabs gen_tabs() {
    Tabs T{};
    unsigned short C[NQ] = {}, R[NQ] = {};
    for (int q = 0; q < NQ; ++q) { C[q] = (unsigned short)(1u << (NQ - 1 - q)); R[q] = C[q]; }
    for (int l = 0; l < NLAYERS; ++l) {
        for (int q = 0; q < NQ; ++q) T.m[l * NQ + q] = C[q];
        for (int g = 0; g < NQ; ++g) {           // sequential — matches verified R2/R3/R4/R7/R9/R10
            int t = (g + 1) % NQ;
            C[g] ^= C[t];
            R[t] ^= R[g];
        }
    }
    for (int q = 0; q < NQ; ++q) T.r[q] = R[q];
    for (int q = 0; q < NQ; ++q) {
        int cnt = 0;
        for (int pos = 0; pos < NQ; ++pos)
            if ((R[q] >> pos) & 1u) { T.qb[q][cnt] = (unsigned char)(NQ - 1 - pos); ++cnt; }
        T.p[q] = cnt;
    }
    T.off[0] = 0;
    for (int q = 0; q < NQ; ++q) T.off[q + 1] = T.off[q] + (1 << T.p[q]);
    for (int q = 0; q < NQ; ++q) {
        int n = 0;
        for (int g = 0; g < NGATES; ++g) {
            if (cpopc((unsigned)(T.m[g] & R[q])) & 1) {
                T.gmask[q][n] = T.m[g];
                T.gidx[q][n]  = (unsigned char)g;
                ++n;
            }
        }
        T.ng[q] = n;
    }
    return T;
}
constexpr Tabs TAB = gen_tabs();

constexpr int calc_maxp() { int m = 0; for (int q = 0; q < NQ; ++q) if (TAB.p[q] > m) m = TAB.p[q]; return m; }
constexpr int MAXP  = calc_maxp();
constexpr int TOTAL = TAB.off[NQ];
static_assert(MAXP <= 8, "bin replica arrays sized for p <= 8");

// ---- recursive gate product: literal bucket index mh, registers only ----
template<int Q, int I>
__device__ __forceinline__ void gates(const float2* __restrict__ w, int t,
                                      float (&Bx)[16], float (&By)[16])
{
    if constexpr (I < TAB.ng[Q]) {
        constexpr int mg = (int)TAB.gmask[Q][I];
        constexpr int ml = mg & 1023;
        constexpr int mh = mg >> 10;
        const float2 wv = w[I];                       // ds_read_b64 broadcast
        const float si = (__popc(t & ml) & 1) ? -wv.y : wv.y;
        const float c  = wv.x;
        const float nx = Bx[mh] * c - By[mh] * si;
        const float ny = Bx[mh] * si + By[mh] * c;
        Bx[mh] = nx; By[mh] = ny;
        gates<Q, I + 1>(w, t, Bx, By);
    }
}

template<int Q>
__device__ __forceinline__ void build_q(const float2* __restrict__ w,
                                        float* __restrict__ binC,
                                        float* __restrict__ binS, int t)
{
    constexpr unsigned r     = TAB.r[Q];
    constexpr unsigned rl    = r & 1023u;
    constexpr unsigned rh    = (r >> 10) & 15u;
    constexpr int      pl    = cpopc(rl);
    constexpr int      ph    = cpopc(rh);
    constexpr int      NU    = 1 << ph;          // distinct high-bin values
    constexpr int      MPG   = 16 >> ph;         // kk's per bin group
    constexpr unsigned nrh   = (~rh) & 15u;
    constexpr unsigned dmask = 63u & ~rl;        // lane bits NOT in rl (group mates)

    // phase 1: 16 complex buckets B[h] = e^{i P[h]}
    float Bx[16], By[16];
    #pragma unroll
    for (int h = 0; h < 16; ++h) { Bx[h] = 1.0f; By[h] = 0.0f; }
    gates<Q, 0>(w, t, Bx, By);

    // phase 2: product-WHT -> B[kk] = (cos d[kk], sin d[kk])
    #pragma unroll
    for (int s = 1; s < 16; s <<= 1) {
        #pragma unroll
        for (int h = 0; h < 16; ++h) {
            if (!(h & s)) {
                const int h1 = h | s;
                const float p1 = Bx[h] * Bx[h1], p2 = By[h] * By[h1];
                const float p3 = Bx[h] * By[h1], p4 = By[h] * Bx[h1];
                Bx[h]  = p1 - p2;  By[h]  = p3 + p4;   // A*B
                Bx[h1] = p1 + p2;  By[h1] = p4 - p3;   // A*conj(B)
            }
        }
    }

    // phase 3: ulow = pext(t, rl) (literal mask -> unrolled)
    unsigned ulow = 0;
    {
        int bi = 0;
        #pragma unroll
        for (int pos = 0; pos < 10; ++pos)
            if ((rl >> pos) & 1u) { ulow |= (((unsigned)t >> pos) & 1u) << bi; ++bi; }
    }
    const int rep = t >> 6;                      // per-wave replica
    float* bc = binC + (rep << MAXP);
    float* bs = binS + (rep << MAXP);

    #pragma unroll
    for (int uh = 0; uh < NU; ++uh) {            // constexpr kk-groups
        float fx = 0.0f, fy = 0.0f;
        #pragma unroll
        for (int mm = 0; mm < MPG; ++mm) {
            const int kk = (int)(cdep((unsigned)uh, rh) | cdep((unsigned)mm, nrh));
            fx += Bx[kk]; fy += By[kk];
        }
        // reduce over group-mate lanes (constexpr shuffle tree): after this,
        // every lane of a group holds the group sum
        #pragma unroll
        for (int bb = 0; bb < 6; ++bb) {
            if ((dmask >> bb) & 1u) {            // folds at compile time
                fx += __shfl_xor(fx, 1 << bb, 64);
                fy += __shfl_xor(fy, 1 << bb, 64);
            }
        }
        const unsigned u = ulow | ((unsigned)uh << pl);
        if (((unsigned)t & dmask) == 0u) {       // one lane per address per wave
            atomicAdd(&bc[u], fx);               // collision-free ds_add_f32
            atomicAdd(&bs[u], fy);
        }
    }
}

// -------- kernel 1: batch-independent bin tables C,S (one block per q) --------
__global__ __launch_bounds__(TB, 4)
void build_tables(const float* __restrict__ params, float* __restrict__ tab)
{
    __shared__ float2 w[NGATES];                 // e^{i theta} per relevant gate
    __shared__ float  binC[NREP << MAXP];
    __shared__ float  binS[NREP << MAXP];

    const int q = blockIdx.x;
    const int t = threadIdx.x;
    const int ng = TAB.ng[q];

    if (t < ng) {
        const float th = params[(int)TAB.gidx[q][t]];
        float s, c; sincosf(th, &s, &c);
        w[t] = make_float2(c, s);
    }
    for (int i = t; i < (NREP << MAXP); i += TB) { binC[i] = 0.0f; binS[i] = 0.0f; }
    __syncthreads();

    switch (q) {
        case 0:  build_q<0 >(w, binC, binS, t); break;
        case 1:  build_q<1 >(w, binC, binS, t); break;
        case 2:  build_q<2 >(w, binC, binS, t); break;
        case 3:  build_q<3 >(w, binC, binS, t); break;
        case 4:  build_q<4 >(w, binC, binS, t); break;
        case 5:  build_q<5 >(w, binC, binS, t); break;
        case 6:  build_q<6 >(w, binC, binS, t); break;
        case 7:  build_q<7 >(w, binC, binS, t); break;
        case 8:  build_q<8 >(w, binC, binS, t); break;
        case 9:  build_q<9 >(w, binC, binS, t); break;
        case 10: build_q<10>(w, binC, binS, t); break;
        case 11: build_q<11>(w, binC, binS, t); break;
        case 12: build_q<12>(w, binC, binS, t); break;
        case 13: build_q<13>(w, binC, binS, t); break;
    }
    __syncthreads();

    // merge replicas; plain global stores (single writer per q — session rule)
    const int nbins = 1 << TAB.p[q];
    const int off   = TAB.off[q];
    for (int i = t; i < nbins; i += TB) {
        float sc = 0.0f, ss = 0.0f;
        #pragma unroll
        for (int rp = 0; rp < NREP; ++rp) {
            sc += binC[(rp << MAXP) + i];
            ss += binS[(rp << MAXP) + i];
        }
        tab[off + i]         = sc;
        tab[TOTAL + off + i] = ss;
    }
}

// -------- kernel 2: per-batch bilinear form (unchanged, R4/R7/R9/R10-verified) ----
__global__ __launch_bounds__(T2)
void qout_kernel(const float* __restrict__ x, const float* __restrict__ tab,
                 float* __restrict__ out)
{
    __shared__ float sx[NQ];
    __shared__ float red[T2 / 64][NQ];

    const int b = blockIdx.x;
    const int t = threadIdx.x;
    if (t < NQ) sx[t] = x[b * NQ + t];
    __syncthreads();

    float acc[NQ];
    #pragma unroll
    for (int q = 0; q < NQ; ++q) acc[q] = 0.0f;

    #pragma unroll
    for (int q = 0; q < NQ; ++q) {               // after unroll, p/off/qb are literals
        const int nb  = 1 << TAB.p[q];
        const int off = TAB.off[q];
        for (int u = t; u < nb; u += T2) {
            float A = 0.0f;
            #pragma unroll
            for (int i = 0; i < TAB.p[q]; ++i) {
                const float xv = sx[TAB.qb[q][i]];
                A += ((u >> i) & 1) ? xv : -xv;
            }
            float s, c;
            sincosf(A, &s, &c);
            acc[q] += c * tab[off + u] + s * tab[TOTAL + off + u];
        }
    }

    #pragma unroll
    for (int q = 0; q < NQ; ++q) {
        #pragma unroll
        for (int o = 32; o > 0; o >>= 1)
            acc[q] += __shfl_down(acc[q], o, 64);
    }
    const int wave = t >> 6;
    const int lane = t & 63;
    if (lane == 0) {
        #pragma unroll
        for (int q = 0; q < NQ; ++q) red[wave][q] = acc[q];
    }
    __syncthreads();
    if (t < NQ) {
        float sum = 0.0f;
        #pragma unroll
        for (int w = 0; w < T2 / 64; ++w) sum += red[w][t];
        out[b * NQ + t] = sum * (1.0f / (float)DIM);
    }
}

extern "C" void kernel_launch(void* const* d_in, const int* in_sizes, int n_in,
                              void* d_out, int out_size, void* d_ws, size_t ws_size,
                              hipStream_t stream) {
    const float* x      = (const float*)d_in[0];   // (512, 14) float32
    const float* params = (const float*)d_in[1];   // (6, 1, 14) float32
    float* out          = (float*)d_out;           // (512, 14) float32
    float* tab          = (float*)d_ws;            // 2*TOTAL floats

    build_tables<<<NQ, TB, 0, stream>>>(params, tab);
    qout_kernel<<<BATCH, T2, 0, stream>>>(x, tab, out);
}

// Round 12
// 67.981 us; speedup vs baseline: 2.3892x; 1.0616x over previous
//
#include <hip/hip_runtime.h>
#include <math.h>

// 14-qubit, 6-layer RX+CNOT-ring circuit, batch 512 — fully collapsed form.
//
// Verified chain (R3/R4/R7/R9/R10/R11 passed end-to-end):
//   out[b][q] = 2^-14 * sum_u [ cos(A_u) C^q_u + sin(A_u) S^q_u ]
//   C^q_u + i S^q_u = sum_{k: pext(k,r_q)=u} e^{i DTheta_k}
//   DTheta_k = sum_{g: <r_q,m_g> odd} (-1)^{popc(k&m_g)} theta_g
//
// R12: bin-free phase 3. R11's ~17 us was its own shuffle tree: __shfl_xor
// lowers to ds_swizzle (LDS pipe) -> ~192 ds-ops/thread on worst q. Fix by
// CHOOSING the thread->k enumeration per q:
//   u = t & (2^p-1),  v = (t>>p) | (kk<<(10-p)),  k = dep(u,r)|dep(v,~r)
// -> bin u is independent of kk: each thread register-sums its 16 WHT
// outputs into ONE bin. p>=6: all lanes distinct u -> one plain ds_write
// pair per thread (no shuffles/atomics); p<6: short tree over bits p..5.
// Gate signs keep the verified structure with constexpr masks:
//   sign_g = parity(t & M_g) ^ parity(kk & H_g)
//   M_g = pext(m_g,r) | ((pext(m_g,~r) & (2^(10-p)-1)) << p)
//   H_g = pext(m_g,~r) >> (10-p)
// pext(k,r) = u exactly matches qout's verified qb[] convention.
// SESSION RULE intact: tab written by exactly ONE block per q.

#define NQ 14
#define DIM 16384
#define NLAYERS 6
#define NGATES (NLAYERS * NQ)   // 84
#define BATCH 512
#define T2 256
#define TB 1024                 // build threads
#define NREP 16                 // bin replicas, one per wave

constexpr int cpopc(unsigned v) { int c = 0; while (v) { c += (int)(v & 1u); v >>= 1; } return c; }

constexpr unsigned cpext(unsigned v, unsigned m) {
    // extract bits of v at set positions of m, LSB-first
    unsigned r = 0; int b = 0;
    for (int pos = 0; pos < 16; ++pos)
        if ((m >> pos) & 1u) { r |= ((v >> pos) & 1u) << b; ++b; }
    return r;
}

struct Tabs {
    unsigned short m[NGATES];        // gate masks (k-bit-position space)
    unsigned short r[NQ];            // readout lag masks
    int p[NQ];                       // popc(r[q])
    int off[NQ + 1];                 // bin-table offsets (prefix sums of 2^p)
    unsigned char qb[NQ][NQ];        // qubit index per set bit of r (LSB-first)
    int ng[NQ];                      // # gates with odd overlap vs r[q]
    unsigned short gmask[NQ][NGATES];
    unsigned char  gidx[NQ][NGATES];
};

constexpr Tabs gen_tabs() {
    Tabs T{};
    unsigned short C[NQ] = {}, R[NQ] = {};
    for (int q = 0; q < NQ; ++q) { C[q] = (unsigned short)(1u << (NQ - 1 - q)); R[q] = C[q]; }
    for (int l = 0; l < NLAYERS; ++l) {
        for (int q = 0; q < NQ; ++q) T.m[l * NQ + q] = C[q];
        for (int g = 0; g < NQ; ++g) {           // sequential — matches all passing rounds
            int t = (g + 1) % NQ;
            C[g] ^= C[t];
            R[t] ^= R[g];
        }
    }
    for (int q = 0; q < NQ; ++q) T.r[q] = R[q];
    for (int q = 0; q < NQ; ++q) {
        int cnt = 0;
        for (int pos = 0; pos < NQ; ++pos)
            if ((R[q] >> pos) & 1u) { T.qb[q][cnt] = (unsigned char)(NQ - 1 - pos); ++cnt; }
        T.p[q] = cnt;
    }
    T.off[0] = 0;
    for (int q = 0; q < NQ; ++q) T.off[q + 1] = T.off[q] + (1 << T.p[q]);
    for (int q = 0; q < NQ; ++q) {
        int n = 0;
        for (int g = 0; g < NGATES; ++g) {
            if (cpopc((unsigned)(T.m[g] & R[q])) & 1) {
                T.gmask[q][n] = T.m[g];
                T.gidx[q][n]  = (unsigned char)g;
                ++n;
            }
        }
        T.ng[q] = n;
    }
    return T;
}
constexpr Tabs TAB = gen_tabs();

constexpr int calc_maxp() { int m = 0; for (int q = 0; q < NQ; ++q) if (TAB.p[q] > m) m = TAB.p[q]; return m; }
constexpr int calc_minp() { int m = 99; for (int q = 0; q < NQ; ++q) if (TAB.p[q] < m) m = TAB.p[q]; return m; }
constexpr int MAXP  = calc_maxp();
constexpr int MINP  = calc_minp();
constexpr int TOTAL = TAB.off[NQ];
static_assert(MAXP <= 8, "u = t & (2^p-1) needs p <= 10; replicas sized for p <= 8");
static_assert(MINP >= 1, "r mask must be nonzero");

// ---- recursive gate product: literal masks, register buckets only ----
template<int Q, int I>
__device__ __forceinline__ void gates(const float2* __restrict__ w, int t,
                                      float (&Bx)[16], float (&By)[16])
{
    if constexpr (I < TAB.ng[Q]) {
        constexpr unsigned r  = TAB.r[Q];
        constexpr unsigned nr = (~r) & 0x3FFFu;
        constexpr int      p  = TAB.p[Q];
        constexpr unsigned mg = TAB.gmask[Q][I];
        constexpr unsigned Ag = cpext(mg, r);                         // p bits
        constexpr unsigned Bg = cpext(mg, nr);                        // 14-p bits
        constexpr unsigned Mg = Ag | ((Bg & ((1u << (10 - p)) - 1u)) << p); // 10-bit
        constexpr unsigned Hg = (Bg >> (10 - p)) & 15u;               // 4-bit class
        const float2 wv = w[I];                       // ds_read_b64 broadcast
        const float si = (__popc((unsigned)t & Mg) & 1) ? -wv.y : wv.y;
        const float c  = wv.x;
        const float nx = Bx[Hg] * c - By[Hg] * si;
        const float ny = Bx[Hg] * si + By[Hg] * c;
        Bx[Hg] = nx; By[Hg] = ny;
        gates<Q, I + 1>(w, t, Bx, By);
    }
}

template<int Q>
__device__ __forceinline__ void build_q(const float2* __restrict__ w,
                                        float* __restrict__ binC,
                                        float* __restrict__ binS, int t)
{
    constexpr int      p       = TAB.p[Q];
    constexpr unsigned lowmask = (1u << p) - 1u;

    // phase 1: 16 complex buckets B[h] = e^{i P[h]} (t-part signs)
    float Bx[16], By[16];
    #pragma unroll
    for (int h = 0; h < 16; ++h) { Bx[h] = 1.0f; By[h] = 0.0f; }
    gates<Q, 0>(w, t, Bx, By);

    // phase 2: product-WHT -> B[kk] = e^{i DTheta(k(t,kk))} (R10-verified)
    #pragma unroll
    for (int s = 1; s < 16; s <<= 1) {
        #pragma unroll
        for (int h = 0; h < 16; ++h) {
            if (!(h & s)) {
                const int h1 = h | s;
                const float p1 = Bx[h] * Bx[h1], p2 = By[h] * By[h1];
                const float p3 = Bx[h] * By[h1], p4 = By[h] * Bx[h1];
                Bx[h]  = p1 - p2;  By[h]  = p3 + p4;   // A*B
                Bx[h1] = p1 + p2;  By[h1] = p4 - p3;   // A*conj(B)
            }
        }
    }

    // phase 3: all 16 kk share bin u = t & lowmask -> register sum
    float fx = 0.0f, fy = 0.0f;
    #pragma unroll
    for (int h = 0; h < 16; ++h) { fx += Bx[h]; fy += By[h]; }

    const unsigned u   = (unsigned)t & lowmask;
    const int      rep = t >> 6;                 // per-wave replica
    float* bc = binC + (rep << MAXP);
    float* bs = binS + (rep << MAXP);

    if constexpr (p >= 6) {
        // lanes of a wave have distinct u; waves separated by replicas:
        // one plain store pair per thread, no shuffles, no atomics.
        bc[u] = fx;
        bs[u] = fy;
    } else {
        // group mates differ in lane bits p..5: short shuffle tree, lead writes
        constexpr unsigned dm = 63u & ~lowmask;
        #pragma unroll
        for (int bb = p; bb < 6; ++bb) {
            fx += __shfl_xor(fx, 1 << bb, 64);
            fy += __shfl_xor(fy, 1 << bb, 64);
        }
        if (((unsigned)t & dm) == 0u) {
            bc[u] = fx;
            bs[u] = fy;
        }
    }
}

// -------- kernel 1: batch-independent bin tables C,S (one block per q) --------
__global__ __launch_bounds__(TB, 4)
void build_tables(const float* __restrict__ params, float* __restrict__ tab)
{
    __shared__ float2 w[NGATES];                 // e^{i theta} per relevant gate
    __shared__ float  binC[NREP << MAXP];
    __shared__ float  binS[NREP << MAXP];

    const int q = blockIdx.x;
    const int t = threadIdx.x;
    const int ng = TAB.ng[q];

    if (t < ng) {
        const float th = params[(int)TAB.gidx[q][t]];
        float s, c; sincosf(th, &s, &c);
        w[t] = make_float2(c, s);
    }
    for (int i = t; i < (NREP << MAXP); i += TB) { binC[i] = 0.0f; binS[i] = 0.0f; }
    __syncthreads();

    switch (q) {
        case 0:  build_q<0 >(w, binC, binS, t); break;
        case 1:  build_q<1 >(w, binC, binS, t); break;
        case 2:  build_q<2 >(w, binC, binS, t); break;
        case 3:  build_q<3 >(w, binC, binS, t); break;
        case 4:  build_q<4 >(w, binC, binS, t); break;
        case 5:  build_q<5 >(w, binC, binS, t); break;
        case 6:  build_q<6 >(w, binC, binS, t); break;
        case 7:  build_q<7 >(w, binC, binS, t); break;
        case 8:  build_q<8 >(w, binC, binS, t); break;
        case 9:  build_q<9 >(w, binC, binS, t); break;
        case 10: build_q<10>(w, binC, binS, t); break;
        case 11: build_q<11>(w, binC, binS, t); break;
        case 12: build_q<12>(w, binC, binS, t); break;
        case 13: build_q<13>(w, binC, binS, t); break;
    }
    __syncthreads();

    // merge replicas; plain global stores (single writer per q — session rule)
    const int nbins = 1 << TAB.p[q];
    const int off   = TAB.off[q];
    for (int i = t; i < nbins; i += TB) {
        float sc = 0.0f, ss = 0.0f;
        #pragma unroll
        for (int rp = 0; rp < NREP; ++rp) {
            sc += binC[(rp << MAXP) + i];
            ss += binS[(rp << MAXP) + i];
        }
        tab[off + i]         = sc;
        tab[TOTAL + off + i] = ss;
    }
}

// -------- kernel 2: per-batch bilinear form (unchanged, verified R4..R11) ----
__global__ __launch_bounds__(T2)
void qout_kernel(const float* __restrict__ x, const float* __restrict__ tab,
                 float* __restrict__ out)
{
    __shared__ float sx[NQ];
    __shared__ float red[T2 / 64][NQ];

    const int b = blockIdx.x;
    const int t = threadIdx.x;
    if (t < NQ) sx[t] = x[b * NQ + t];
    __syncthreads();

    float acc[NQ];
    #pragma unroll
    for (int q = 0; q < NQ; ++q) acc[q] = 0.0f;

    #pragma unroll
    for (int q = 0; q < NQ; ++q) {               // after unroll, p/off/qb are literals
        const int nb  = 1 << TAB.p[q];
        const int off = TAB.off[q];
        for (int u = t; u < nb; u += T2) {
            float A = 0.0f;
            #pragma unroll
            for (int i = 0; i < TAB.p[q]; ++i) {
                const float xv = sx[TAB.qb[q][i]];
                A += ((u >> i) & 1) ? xv : -xv;
            }
            float s, c;
            sincosf(A, &s, &c);
            acc[q] += c * tab[off + u] + s * tab[TOTAL + off + u];
        }
    }

    #pragma unroll
    for (int q = 0; q < NQ; ++q) {
        #pragma unroll
        for (int o = 32; o > 0; o >>= 1)
            acc[q] += __shfl_down(acc[q], o, 64);
    }
    const int wave = t >> 6;
    const int lane = t & 63;
    if (lane == 0) {
        #pragma unroll
        for (int q = 0; q < NQ; ++q) red[wave][q] = acc[q];
    }
    __syncthreads();
    if (t < NQ) {
        float sum = 0.0f;
        #pragma unroll
        for (int w = 0; w < T2 / 64; ++w) sum += red[w][t];
        out[b * NQ + t] = sum * (1.0f / (float)DIM);
    }
}

extern "C" void kernel_launch(void* const* d_in, const int* in_sizes, int n_in,
                              void* d_out, int out_size, void* d_ws, size_t ws_size,
                              hipStream_t stream) {
    const float* x      = (const float*)d_in[0];   // (512, 14) float32
    const float* params = (const float*)d_in[1];   // (6, 1, 14) float32
    float* out          = (float*)d_out;           // (512, 14) float32
    float* tab          = (float*)d_ws;            // 2*TOTAL floats

    build_tables<<<NQ, TB, 0, stream>>>(params, tab);
    qout_kernel<<<BATCH, T2, 0, stream>>>(x, tab, out);
}